// Round 5
// baseline (293.766 us; speedup 1.0000x reference)
//
#include <hip/hip_runtime.h>
#include <math.h>
#include <float.h>
#include <stdint.h>

#define NN 1024
#define DD 128
#define HH 8
#define HDIM 16
#define KTOP 16
#define SCP 1032            // padded j-stride for h-major sc

__device__ __forceinline__ float wred_sum(float v) {
#pragma unroll
  for (int off = 32; off > 0; off >>= 1) v += __shfl_xor(v, off, 64);
  return v;
}

// DPP lane-reduce add (VALU pipe, no LDS): v += v[partner]
template <int CTRL>
__device__ __forceinline__ float dpp_add(float v) {
  int x = __builtin_amdgcn_update_dpp(0, __float_as_int(v), CTRL, 0xF, 0xF, true);
  return v + __int_as_float(x);
}
#define DPP_XOR1 0xB1   // quad_perm(1,0,3,2)
#define DPP_XOR2 0x4E   // quad_perm(2,3,0,1)
#define DPP_ROR4 0x124  // row_ror:4 (16-lane row)
#define DPP_ROR8 0x128  // row_ror:8

// ---------------- K1: q,k,v = h @ W{q,k,v} + b ----------------
__global__ __launch_bounds__(128) void k_qkv(
    const float* __restrict__ h,
    const float* __restrict__ Wq, const float* __restrict__ bq,
    const float* __restrict__ Wk, const float* __restrict__ bk,
    const float* __restrict__ Wv, const float* __restrict__ bv,
    float* __restrict__ q, float* __restrict__ k, float* __restrict__ v) {
  __shared__ float hrow[4][DD];
  const int t = threadIdx.x;
  const int i0 = blockIdx.x * 4;
#pragma unroll
  for (int r = 0; r < 4; ++r) hrow[r][t] = h[(i0 + r) * DD + t];
  __syncthreads();
  const float* W[3] = {Wq, Wk, Wv};
  const float* B[3] = {bq, bk, bv};
  float* O[3] = {q, k, v};
#pragma unroll
  for (int m = 0; m < 3; ++m) {
    float a0 = 0.f, a1 = 0.f, a2 = 0.f, a3 = 0.f;
    const float* Wm = W[m];
#pragma unroll 8
    for (int c = 0; c < DD; ++c) {
      float w = Wm[c * DD + t];
      a0 += hrow[0][c] * w; a1 += hrow[1][c] * w;
      a2 += hrow[2][c] * w; a3 += hrow[3][c] * w;
    }
    float b = B[m][t];
    float* Om = O[m];
    Om[(i0 + 0) * DD + t] = a0 + b;
    Om[(i0 + 1) * DD + t] = a1 + b;
    Om[(i0 + 2) * DD + t] = a2 + b;
    Om[(i0 + 3) * DD + t] = a3 + b;
  }
}

// ---------------- K2: fused scores + top-k + softmax + PV ----------------
// Block (128 thr) per node i. Phase 0: qk scores from L2-resident k.
// Main loop: e streamed HBM->VGPR, block-staggered start tile (i&63) to
// decorrelate HBM channel phase across the 1024 concurrent streams;
// depth-2 register double-buffer (A/B, static names).
__global__ __launch_bounds__(128, 2) void k_attn(
    const float* __restrict__ e, const float* __restrict__ We, const float* __restrict__ be,
    const float* __restrict__ q, const float* __restrict__ kk, const float* __restrict__ v,
    float* __restrict__ hattn) {
  __shared__ float sc[HH * SCP];       // 33 KB, h-major padded
  const int tid = threadIdx.x;
  const int lane = tid & 63;
  const int wv = tid >> 6;             // 0..1
  const int i = blockIdx.x;

  const int lrow = lane >> 4;          // 0..3
  const int c16 = lane & 15;           // column chunk
  const int c0 = c16 * 8;              // 8 columns of the row
  const int rb = wv * 8 + lrow;        // rows rb and rb+4 within a 16-row tile
  const int t0 = i & 63;               // staggered start tile

  const float* ei = e + ((size_t)i << 17);

#define LOADSET(X0, X1, X2, X3, T)                                        \
  {                                                                        \
    int tt_ = (t0 + (T)) & 63;                                             \
    const float* xp_ = ei + (size_t)tt_ * (16 * DD) + (size_t)rb * DD + c0;\
    X0 = *(const float4*)(xp_);          X1 = *(const float4*)(xp_ + 4);   \
    X2 = *(const float4*)(xp_ + 4 * DD); X3 = *(const float4*)(xp_ + 4 * DD + 4); \
  }

  // issue first two tiles' e loads before the qk phase (latency hidden there)
  float4 A0, A1, A2, A3, B0, B1, B2, B3;
  LOADSET(A0, A1, A2, A3, 0)
  LOADSET(B0, B1, B2, B3, 1)

  // weights: We[c0+cl][h] for cl in 0..7 -> 16 f4 regs
  float4 w[16];
#pragma unroll
  for (int cl = 0; cl < 8; ++cl) {
    w[cl * 2]     = *(const float4*)(We + (c0 + cl) * HH);
    w[cl * 2 + 1] = *(const float4*)(We + (c0 + cl) * HH + 4);
  }

  // ---- phase 0: sc[h][j] = be[h] + 0.25*dot(q[i,h,:], k[j,h,:]) ----
  {
    const int h = tid & 7;
    const int jsub = tid >> 3;              // 0..15
    const float* qp = q + (size_t)i * DD + h * HDIM;
    float4 q0 = *(const float4*)(qp);
    float4 q1 = *(const float4*)(qp + 4);
    float4 q2 = *(const float4*)(qp + 8);
    float4 q3 = *(const float4*)(qp + 12);
    const float beh = be[h];
#pragma unroll 2
    for (int jm = 0; jm < 64; ++jm) {
      int j = jm * 16 + jsub;
      const float* kp = kk + (size_t)j * DD + h * HDIM;
      float4 k0 = *(const float4*)(kp);
      float4 k1 = *(const float4*)(kp + 4);
      float4 k2 = *(const float4*)(kp + 8);
      float4 k3 = *(const float4*)(kp + 12);
      float d = q0.x*k0.x + q0.y*k0.y + q0.z*k0.z + q0.w*k0.w
              + q1.x*k1.x + q1.y*k1.y + q1.z*k1.z + q1.w*k1.w
              + q2.x*k2.x + q2.y*k2.y + q2.z*k2.z + q2.w*k2.w
              + q3.x*k3.x + q3.y*k3.y + q3.z*k3.z + q3.w*k3.w;
      sc[h * SCP + j] = beh + 0.25f * d;
    }
  }
  __syncthreads();

#define COMPUTE(X0, X1, X2, X3, T)                                         \
  {                                                                        \
    int tt_ = (t0 + (T)) & 63;                                             \
    const int j_ = tt_ * 16 + rb;                                          \
    float acca[8] = {0, 0, 0, 0, 0, 0, 0, 0};                              \
    float accb[8] = {0, 0, 0, 0, 0, 0, 0, 0};                              \
    const float eva[8] = {X0.x, X0.y, X0.z, X0.w, X1.x, X1.y, X1.z, X1.w}; \
    const float evb[8] = {X2.x, X2.y, X2.z, X2.w, X3.x, X3.y, X3.z, X3.w}; \
    _Pragma("unroll")                                                      \
    for (int cl = 0; cl < 8; ++cl) {                                       \
      float4 wlo = w[cl * 2], whi = w[cl * 2 + 1];                         \
      float a_ = eva[cl], b_ = evb[cl];                                    \
      acca[0] += a_ * wlo.x; acca[1] += a_ * wlo.y;                        \
      acca[2] += a_ * wlo.z; acca[3] += a_ * wlo.w;                        \
      acca[4] += a_ * whi.x; acca[5] += a_ * whi.y;                        \
      acca[6] += a_ * whi.z; acca[7] += a_ * whi.w;                        \
      accb[0] += b_ * wlo.x; accb[1] += b_ * wlo.y;                        \
      accb[2] += b_ * wlo.z; accb[3] += b_ * wlo.w;                        \
      accb[4] += b_ * whi.x; accb[5] += b_ * whi.y;                        \
      accb[6] += b_ * whi.z; accb[7] += b_ * whi.w;                        \
    }                                                                      \
    _Pragma("unroll")                                                      \
    for (int hh = 0; hh < 8; ++hh) {                                       \
      acca[hh] = dpp_add<DPP_XOR1>(acca[hh]);                              \
      acca[hh] = dpp_add<DPP_XOR2>(acca[hh]);                              \
      acca[hh] = dpp_add<DPP_ROR4>(acca[hh]);                              \
      acca[hh] = dpp_add<DPP_ROR8>(acca[hh]);                              \
      accb[hh] = dpp_add<DPP_XOR1>(accb[hh]);                              \
      accb[hh] = dpp_add<DPP_XOR2>(accb[hh]);                              \
      accb[hh] = dpp_add<DPP_ROR4>(accb[hh]);                              \
      accb[hh] = dpp_add<DPP_ROR8>(accb[hh]);                              \
    }                                                                      \
    if ((c16 & 1) == 0) {                                                  \
      const int h_ = c16 >> 1;                                             \
      float sa = acca[0], sb = accb[0];                                    \
      _Pragma("unroll")                                                    \
      for (int hh = 1; hh < 8; ++hh) {                                     \
        if (h_ == hh) { sa = acca[hh]; sb = accb[hh]; }                    \
      }                                                                    \
      sc[h_ * SCP + j_] += sa;                                             \
      sc[h_ * SCP + j_ + 4] += sb;                                         \
    }                                                                      \
  }

  // ---- main loop: 2x unrolled A/B register double-buffer, depth-2 prefetch ----
  for (int t = 0; t < 64; t += 2) {
    COMPUTE(A0, A1, A2, A3, t)
    LOADSET(A0, A1, A2, A3, t + 2)       // wraps at end (redundant, harmless)
    COMPUTE(B0, B1, B2, B3, t + 1)
    LOADSET(B0, B1, B2, B3, t + 3)
  }
  __syncthreads();

  // ---- phase 3: per head top-16 (lowest-j ties), softmax, PV ----
#pragma unroll 1
  for (int hp = 0; hp < 4; ++hp) {
    const int h = wv * 4 + hp;
    float val[16];
#pragma unroll
    for (int s = 0; s < 16; ++s) val[s] = sc[h * SCP + s * 64 + lane];
    int selj[16];
    float wgt[16];
    float vmax = 0.f, denom = 0.f;
#pragma unroll
    for (int t = 0; t < KTOP; ++t) {
      float bv = -FLT_MAX;
      int bj = 0x7FFFFFFF;
#pragma unroll
      for (int s = 0; s < 16; ++s) {
        float vs = val[s];
        int jj = s * 64 + lane;
        if (vs > bv) { bv = vs; bj = jj; }
      }
#pragma unroll
      for (int off = 32; off > 0; off >>= 1) {
        float ov = __shfl_xor(bv, off, 64);
        int oj = __shfl_xor(bj, off, 64);
        if (ov > bv || (ov == bv && oj < bj)) { bv = ov; bj = oj; }
      }
      selj[t] = bj;
      if (t == 0) vmax = bv;
      float wexp = expf(bv - vmax);
      wgt[t] = wexp;
      denom += wexp;
      const int so = bj >> 6;
      if ((bj & 63) == lane) {
#pragma unroll
        for (int s = 0; s < 16; ++s)
          if (s == so) val[s] = -FLT_MAX;
      }
    }
    const float inv = 1.0f / denom;
    const int d = lane & 15;
    float acc = 0.f;
#pragma unroll
    for (int t = 0; t < KTOP; ++t)
      acc += wgt[t] * v[(size_t)selj[t] * DD + h * HDIM + d];
    if (lane < 16) hattn[i * DD + h * HDIM + d] = acc * inv;
  }
}

// ---------------- K3: Wo proj + residual + LN1 + LSTMCell(zero state) ----------------
__global__ __launch_bounds__(128) void k_post1(
    const float* __restrict__ h, const float* __restrict__ hattn,
    const float* __restrict__ Wo, const float* __restrict__ bo,
    const float* __restrict__ Wih, const float* __restrict__ bih, const float* __restrict__ bhh,
    const float* __restrict__ ln1g, const float* __restrict__ ln1b,
    float* __restrict__ x2, float* __restrict__ outh, float* __restrict__ outc) {
  __shared__ float arow[4][DD];
  __shared__ float x1s[4][DD];
  __shared__ float redS[4][2], redQ[4][2];
  const int t = threadIdx.x;
  const int i0 = blockIdx.x * 4;
#pragma unroll
  for (int r = 0; r < 4; ++r) arow[r][t] = hattn[(i0 + r) * DD + t];
  __syncthreads();
  float o0 = 0.f, o1 = 0.f, o2 = 0.f, o3 = 0.f;
#pragma unroll 4
  for (int c = 0; c < DD; ++c) {
    float w = Wo[c * DD + t];
    o0 += arow[0][c] * w; o1 += arow[1][c] * w;
    o2 += arow[2][c] * w; o3 += arow[3][c] * w;
  }
  float ovals[4] = {o0, o1, o2, o3};
  const float bov = bo[t], g1 = ln1g[t], b1 = ln1b[t];
#pragma unroll
  for (int r = 0; r < 4; ++r) {
    float res = h[(i0 + r) * DD + t] + ovals[r] + bov;
    float s1 = wred_sum(res), s2 = wred_sum(res * res);
    if ((t & 63) == 0) { redS[r][t >> 6] = s1; redQ[r][t >> 6] = s2; }
    __syncthreads();
    float mu = (redS[r][0] + redS[r][1]) * (1.f / 128.f);
    float var = (redQ[r][0] + redQ[r][1]) * (1.f / 128.f) - mu * mu;
    x1s[r][t] = g1 * (res - mu) * rsqrtf(var + 1e-5f) + b1;
  }
  __syncthreads();
  float gi[4] = {0, 0, 0, 0}, gg[4] = {0, 0, 0, 0}, go[4] = {0, 0, 0, 0};
  for (int c = 0; c < DD; ++c) {
    float wI = Wih[(t)*DD + c];
    float wG = Wih[(t + 256) * DD + c];
    float wO = Wih[(t + 384) * DD + c];
#pragma unroll
    for (int r = 0; r < 4; ++r) {
      float xv = x1s[r][c];
      gi[r] += xv * wI; gg[r] += xv * wG; go[r] += xv * wO;
    }
  }
  const float biI = bih[t] + bhh[t];
  const float biG = bih[t + 256] + bhh[t + 256];
  const float biO = bih[t + 384] + bhh[t + 384];
#pragma unroll
  for (int r = 0; r < 4; ++r) {
    float iv = 1.f / (1.f + expf(-(gi[r] + biI)));
    float gv = tanhf(gg[r] + biG);
    float ov = 1.f / (1.f + expf(-(go[r] + biO)));
    float cn = iv * gv;
    float hn = ov * tanhf(cn);
    outh[(i0 + r) * DD + t] = hn;
    outc[(i0 + r) * DD + t] = cn;
    x2[(i0 + r) * DD + t] = x1s[r][t] + hn;
  }
}

// ---------------- K4a: GraphNorm partial column sums ----------------
__global__ __launch_bounds__(256) void k_gncol(const float* __restrict__ x2,
                                               float* __restrict__ pS, float* __restrict__ pQ) {
  const int t = threadIdx.x, b = blockIdx.x;
  const int c = t & 127, half = t >> 7;
  const int r0 = b * 16 + half * 8;
  float s = 0.f, qq = 0.f;
#pragma unroll
  for (int r = 0; r < 8; ++r) {
    float v = x2[(r0 + r) * DD + c];
    s += v; qq += v * v;
  }
  pS[(b * 2 + half) * DD + c] = s;
  pQ[(b * 2 + half) * DD + c] = qq;
}

// ---------------- K4b: finalize stats ----------------
__global__ __launch_bounds__(128) void k_gnfin(const float* __restrict__ pS,
                                               const float* __restrict__ pQ,
                                               float* __restrict__ stats) {
  const int c = threadIdx.x;
  float s = 0.f, qq = 0.f;
#pragma unroll 8
  for (int kk = 0; kk < 128; ++kk) { s += pS[kk * DD + c]; qq += pQ[kk * DD + c]; }
  float mu = s * (1.f / 1024.f);
  float var = qq * (1.f / 1024.f) - mu * mu;
  stats[c] = mu;
  stats[DD + c] = rsqrtf(var + 1e-5f);
}

// ---------------- K5: GraphNorm apply + FFN + residual + LN2 ----------------
__global__ __launch_bounds__(256) void k_ffn(
    const float* __restrict__ x2, const float* __restrict__ stats,
    const float* __restrict__ gng, const float* __restrict__ gnb,
    const float* __restrict__ Wf1, const float* __restrict__ bf1,
    const float* __restrict__ Wf2, const float* __restrict__ bf2,
    const float* __restrict__ ln2g, const float* __restrict__ ln2b,
    float* __restrict__ out) {
  __shared__ float x3s[4][DD];
  __shared__ float hid[4][512];
  __shared__ float redC[4][256];
  __shared__ float redS[4][4], redQ[4][4];
  const int t = threadIdx.x;
  const int i0 = blockIdx.x * 4;
  for (int idx = t; idx < 4 * DD; idx += 256) {
    int r = idx >> 7, c = idx & 127;
    float vv = x2[(i0 + r) * DD + c];
    x3s[r][c] = gng[c] * (vv - stats[c]) * stats[DD + c] + gnb[c];
  }
  __syncthreads();
  {
    float a0[4] = {0, 0, 0, 0}, a1[4] = {0, 0, 0, 0};
#pragma unroll 2
    for (int c = 0; c < DD; ++c) {
      float w1 = Wf1[c * 512 + t];
      float w2 = Wf1[c * 512 + t + 256];
#pragma unroll
      for (int r = 0; r < 4; ++r) {
        float xv = x3s[r][c];
        a0[r] += xv * w1; a1[r] += xv * w2;
      }
    }
    float bb1 = bf1[t], bb2 = bf1[t + 256];
#pragma unroll
    for (int r = 0; r < 4; ++r) {
      hid[r][t] = fmaxf(a0[r] + bb1, 0.f);
      hid[r][t + 256] = fmaxf(a1[r] + bb2, 0.f);
    }
  }
  __syncthreads();
  const int d = t & 127, half = t >> 7;
  {
    float a[4] = {0, 0, 0, 0};
    for (int uu = 0; uu < 256; ++uu) {
      int u = half * 256 + uu;
      float w = Wf2[u * DD + d];
#pragma unroll
      for (int r = 0; r < 4; ++r) a[r] += hid[r][u] * w;
    }
#pragma unroll
    for (int r = 0; r < 4; ++r) redC[r][t] = a[r];
  }
  __syncthreads();
  const int lane = t & 63, wvv = t >> 6;
#pragma unroll 1
  for (int r = 0; r < 4; ++r) {
    float z = 0.f;
    if (t < DD) z = x3s[r][t] + redC[r][t] + redC[r][t + 128] + bf2[t];
    float s1 = wred_sum(z), s2 = wred_sum(z * z);
    if (lane == 0) { redS[r][wvv] = s1; redQ[r][wvv] = s2; }
    __syncthreads();
    float sum = redS[r][0] + redS[r][1] + redS[r][2] + redS[r][3];
    float sq = redQ[r][0] + redQ[r][1] + redQ[r][2] + redQ[r][3];
    float mu = sum * (1.f / 128.f);
    float var = sq * (1.f / 128.f) - mu * mu;
    float rs = rsqrtf(var + 1e-5f);
    if (t < DD) out[(i0 + r) * DD + t] = ln2g[t] * (z - mu) * rs + ln2b[t];
  }
}

extern "C" void kernel_launch(void* const* d_in, const int* in_sizes, int n_in,
                              void* d_out, int out_size, void* d_ws, size_t ws_size,
                              hipStream_t stream) {
  const float* h   = (const float*)d_in[0];
  const float* e   = (const float*)d_in[1];
  const float* Wq  = (const float*)d_in[3];
  const float* bq  = (const float*)d_in[4];
  const float* Wk  = (const float*)d_in[5];
  const float* bk  = (const float*)d_in[6];
  const float* Wv  = (const float*)d_in[7];
  const float* bv  = (const float*)d_in[8];
  const float* We  = (const float*)d_in[9];
  const float* be  = (const float*)d_in[10];
  const float* Wo  = (const float*)d_in[11];
  const float* bo  = (const float*)d_in[12];
  const float* Wf1 = (const float*)d_in[13];
  const float* bf1 = (const float*)d_in[14];
  const float* Wf2 = (const float*)d_in[15];
  const float* bf2 = (const float*)d_in[16];
  const float* Wih = (const float*)d_in[17];
  const float* bih = (const float*)d_in[19];
  const float* bhh = (const float*)d_in[20];
  const float* gng = (const float*)d_in[21];
  const float* gnb = (const float*)d_in[22];
  const float* l1g = (const float*)d_in[23];
  const float* l1b = (const float*)d_in[24];
  const float* l2g = (const float*)d_in[25];
  const float* l2b = (const float*)d_in[26];

  float* W = (float*)d_ws;
  float* q     = W;
  float* k     = W + 131072;
  float* v     = W + 262144;
  float* hattn = W + 393216;
  float* x2    = W + 524288;
  float* stats = W + 655360;
  float* pS    = W + 655616;
  float* pQ    = W + 672000;

  float* out  = (float*)d_out;
  float* outh = out + 131072;
  float* outc = out + 262144;

  hipLaunchKernelGGL(k_qkv, dim3(256), dim3(128), 0, stream,
                     h, Wq, bq, Wk, bk, Wv, bv, q, k, v);
  hipLaunchKernelGGL(k_attn, dim3(1024), dim3(128), 0, stream,
                     e, We, be, q, k, v, hattn);
  hipLaunchKernelGGL(k_post1, dim3(256), dim3(128), 0, stream,
                     h, hattn, Wo, bo, Wih, bih, bhh, l1g, l1b, x2, outh, outc);
  hipLaunchKernelGGL(k_gncol, dim3(64), dim3(256), 0, stream, x2, pS, pQ);
  hipLaunchKernelGGL(k_gnfin, dim3(1), dim3(128), 0, stream, pS, pQ, stats);
  hipLaunchKernelGGL(k_ffn, dim3(256), dim3(256), 0, stream,
                     x2, stats, gng, gnb, Wf1, bf1, Wf2, bf2, l2g, l2b, out);
}

// Round 6
// 274.323 us; speedup vs baseline: 1.0709x; 1.0709x over previous
//
#include <hip/hip_runtime.h>
#include <math.h>
#include <float.h>
#include <stdint.h>

#define NN 1024
#define DD 128
#define HH 8
#define HDIM 16
#define KTOP 16
#define SCP 1032            // padded j-stride for h-major sc

__device__ __forceinline__ float wred_sum(float v) {
#pragma unroll
  for (int off = 32; off > 0; off >>= 1) v += __shfl_xor(v, off, 64);
  return v;
}

// DPP lane-reduce add (VALU pipe, no LDS): v += v[partner]
template <int CTRL>
__device__ __forceinline__ float dpp_add(float v) {
  int x = __builtin_amdgcn_update_dpp(0, __float_as_int(v), CTRL, 0xF, 0xF, true);
  return v + __int_as_float(x);
}
#define DPP_XOR1 0xB1   // quad_perm(1,0,3,2)
#define DPP_XOR2 0x4E   // quad_perm(2,3,0,1)
#define DPP_ROR4 0x124  // row_ror:4 (16-lane row)
#define DPP_ROR8 0x128  // row_ror:8

// ---------------- K1: q,k,v = h @ W{q,k,v} + b ----------------
__global__ __launch_bounds__(128) void k_qkv(
    const float* __restrict__ h,
    const float* __restrict__ Wq, const float* __restrict__ bq,
    const float* __restrict__ Wk, const float* __restrict__ bk,
    const float* __restrict__ Wv, const float* __restrict__ bv,
    float* __restrict__ q, float* __restrict__ k, float* __restrict__ v) {
  __shared__ float hrow[4][DD];
  const int t = threadIdx.x;
  const int i0 = blockIdx.x * 4;
#pragma unroll
  for (int r = 0; r < 4; ++r) hrow[r][t] = h[(i0 + r) * DD + t];
  __syncthreads();
  const float* W[3] = {Wq, Wk, Wv};
  const float* B[3] = {bq, bk, bv};
  float* O[3] = {q, k, v};
#pragma unroll
  for (int m = 0; m < 3; ++m) {
    float a0 = 0.f, a1 = 0.f, a2 = 0.f, a3 = 0.f;
    const float* Wm = W[m];
#pragma unroll 8
    for (int c = 0; c < DD; ++c) {
      float w = Wm[c * DD + t];
      a0 += hrow[0][c] * w; a1 += hrow[1][c] * w;
      a2 += hrow[2][c] * w; a3 += hrow[3][c] * w;
    }
    float b = B[m][t];
    float* Om = O[m];
    Om[(i0 + 0) * DD + t] = a0 + b;
    Om[(i0 + 1) * DD + t] = a1 + b;
    Om[(i0 + 2) * DD + t] = a2 + b;
    Om[(i0 + 3) * DD + t] = a3 + b;
  }
}

// ---------------- K2: fused scores + top-k + softmax + PV ----------------
// Block (256 thr = 4 waves) per node i. e streamed HBM->VGPR with fused qk
// (R4 structure); 32-row tiles; 3 waves/SIMD for latency hiding.
__global__ __launch_bounds__(256, 3) void k_attn(
    const float* __restrict__ e, const float* __restrict__ We, const float* __restrict__ be,
    const float* __restrict__ q, const float* __restrict__ kk, const float* __restrict__ v,
    float* __restrict__ hattn) {
  __shared__ float sc[HH * SCP];       // 33 KB, h-major padded
  const int tid = threadIdx.x;
  const int lane = tid & 63;
  const int wv = tid >> 6;             // 0..3
  const int i = blockIdx.x;

  const int lrow = lane >> 4;          // 0..3
  const int c16 = lane & 15;           // column chunk
  const int c0 = c16 * 8;              // 8 columns, inside head (c16>>1)'s slice
  const int rb = wv * 8 + lrow;        // rows rb and rb+4 within the 32-row tile

  // weights: We[c0+cl][h] for cl in 0..7 -> 16 f4 regs
  float4 w[16];
#pragma unroll
  for (int cl = 0; cl < 8; ++cl) {
    w[cl * 2]     = *(const float4*)(We + (c0 + cl) * HH);
    w[cl * 2 + 1] = *(const float4*)(We + (c0 + cl) * HH + 4);
  }
  // q slice (pre-scaled by 1/sqrt(16)); head h=c16>>1, dims c0..c0+8
  float4 q0 = *(const float4*)(q + (size_t)i * DD + c0);
  float4 q1 = *(const float4*)(q + (size_t)i * DD + c0 + 4);
  q0.x *= 0.25f; q0.y *= 0.25f; q0.z *= 0.25f; q0.w *= 0.25f;
  q1.x *= 0.25f; q1.y *= 0.25f; q1.z *= 0.25f; q1.w *= 0.25f;
  const float behv = be[c16 >> 1];

  const float* ei = e + ((size_t)i << 17);
  const float* pa = ei + (size_t)rb * DD + c0;   // row a, tile 0
  const float* pb = pa + 4 * DD;                 // row b (rb+4)
  const float* ka = kk + (size_t)rb * DD + c0;
  const float* kb = ka + 4 * DD;

  // prologue: iter 0 loads
  float4 ea0 = *(const float4*)(pa);     float4 ea1 = *(const float4*)(pa + 4);
  float4 eb0 = *(const float4*)(pb);     float4 eb1 = *(const float4*)(pb + 4);
  float4 Ka0 = *(const float4*)(ka);     float4 Ka1 = *(const float4*)(ka + 4);
  float4 Kb0 = *(const float4*)(kb);     float4 Kb1 = *(const float4*)(kb + 4);

  for (int t = 0; t < 32; ++t) {         // 32 tiles x 32 rows
    float4 na0, na1, nb0, nb1, nKa0, nKa1, nKb0, nKb1;
    const bool more = (t + 1 < 32);
    if (more) {                          // depth-1 prefetch of tile t+1
      const float* xa = pa + (size_t)(t + 1) * (32 * DD);
      const float* xb = xa + 4 * DD;
      const float* ya = ka + (size_t)(t + 1) * (32 * DD);
      const float* yb = ya + 4 * DD;
      na0 = *(const float4*)(xa);  na1 = *(const float4*)(xa + 4);
      nb0 = *(const float4*)(xb);  nb1 = *(const float4*)(xb + 4);
      nKa0 = *(const float4*)(ya); nKa1 = *(const float4*)(ya + 4);
      nKb0 = *(const float4*)(yb); nKb1 = *(const float4*)(yb + 4);
    }

    float acca[8] = {0,0,0,0,0,0,0,0};
    float accb[8] = {0,0,0,0,0,0,0,0};
    const float eva[8] = {ea0.x, ea0.y, ea0.z, ea0.w, ea1.x, ea1.y, ea1.z, ea1.w};
    const float evb[8] = {eb0.x, eb0.y, eb0.z, eb0.w, eb1.x, eb1.y, eb1.z, eb1.w};
#pragma unroll
    for (int cl = 0; cl < 8; ++cl) {
      float4 wlo = w[cl * 2], whi = w[cl * 2 + 1];
      float a = eva[cl], b = evb[cl];
      acca[0] += a * wlo.x; acca[1] += a * wlo.y; acca[2] += a * wlo.z; acca[3] += a * wlo.w;
      acca[4] += a * whi.x; acca[5] += a * whi.y; acca[6] += a * whi.z; acca[7] += a * whi.w;
      accb[0] += b * wlo.x; accb[1] += b * wlo.y; accb[2] += b * wlo.z; accb[3] += b * wlo.w;
      accb[4] += b * whi.x; accb[5] += b * whi.y; accb[6] += b * whi.z; accb[7] += b * whi.w;
    }
    float qka = q0.x*Ka0.x + q0.y*Ka0.y + q0.z*Ka0.z + q0.w*Ka0.w
              + q1.x*Ka1.x + q1.y*Ka1.y + q1.z*Ka1.z + q1.w*Ka1.w;
    float qkb = q0.x*Kb0.x + q0.y*Kb0.y + q0.z*Kb0.z + q0.w*Kb0.w
              + q1.x*Kb1.x + q1.y*Kb1.y + q1.z*Kb1.z + q1.w*Kb1.w;

    // allreduce over the 16 lanes of this DPP row (VALU pipe)
#pragma unroll
    for (int hh = 0; hh < 8; ++hh) {
      acca[hh] = dpp_add<DPP_XOR1>(acca[hh]);
      acca[hh] = dpp_add<DPP_XOR2>(acca[hh]);
      acca[hh] = dpp_add<DPP_ROR4>(acca[hh]);
      acca[hh] = dpp_add<DPP_ROR8>(acca[hh]);
      accb[hh] = dpp_add<DPP_XOR1>(accb[hh]);
      accb[hh] = dpp_add<DPP_XOR2>(accb[hh]);
      accb[hh] = dpp_add<DPP_ROR4>(accb[hh]);
      accb[hh] = dpp_add<DPP_ROR8>(accb[hh]);
    }
    qka = dpp_add<DPP_XOR1>(qka);   // head = c16>>1 spans lanes {2h,2h+1}
    qkb = dpp_add<DPP_XOR1>(qkb);

    if ((c16 & 1) == 0) {            // writer lane c16=2h holds acc[h] and qk(h)
      const int h = c16 >> 1;
      float sa = acca[0], sb = accb[0];
#pragma unroll
      for (int hh = 1; hh < 8; ++hh) {
        if (h == hh) { sa = acca[hh]; sb = accb[hh]; }
      }
      const int j = t * 32 + rb;
      sc[h * SCP + j]     = sa + qka + behv;
      sc[h * SCP + j + 4] = sb + qkb + behv;
    }

    if (more) {
      ea0 = na0; ea1 = na1; eb0 = nb0; eb1 = nb1;
      Ka0 = nKa0; Ka1 = nKa1; Kb0 = nKb0; Kb1 = nKb1;
    }
  }
  __syncthreads();

  // ---- phase 3: per head top-16 (lowest-j ties), softmax, PV. 2 heads/wave ----
#pragma unroll 1
  for (int hp = 0; hp < 2; ++hp) {
    const int h = wv * 2 + hp;
    float val[16];
#pragma unroll
    for (int s = 0; s < 16; ++s) val[s] = sc[h * SCP + s * 64 + lane];
    int selj[16];
    float wgt[16];
    float vmax = 0.f, denom = 0.f;
#pragma unroll
    for (int t = 0; t < KTOP; ++t) {
      float bv = -FLT_MAX;
      int bj = 0x7FFFFFFF;
#pragma unroll
      for (int s = 0; s < 16; ++s) {
        float vs = val[s];
        int jj = s * 64 + lane;
        if (vs > bv) { bv = vs; bj = jj; }
      }
#pragma unroll
      for (int off = 32; off > 0; off >>= 1) {
        float ov = __shfl_xor(bv, off, 64);
        int oj = __shfl_xor(bj, off, 64);
        if (ov > bv || (ov == bv && oj < bj)) { bv = ov; bj = oj; }
      }
      selj[t] = bj;
      if (t == 0) vmax = bv;
      float wexp = expf(bv - vmax);
      wgt[t] = wexp;
      denom += wexp;
      const int so = bj >> 6;
      if ((bj & 63) == lane) {
#pragma unroll
        for (int s = 0; s < 16; ++s)
          if (s == so) val[s] = -FLT_MAX;
      }
    }
    const float inv = 1.0f / denom;
    const int d = lane & 15;
    float acc = 0.f;
#pragma unroll
    for (int t = 0; t < KTOP; ++t)
      acc += wgt[t] * v[(size_t)selj[t] * DD + h * HDIM + d];
    if (lane < 16) hattn[i * DD + h * HDIM + d] = acc * inv;
  }
}

// ---------------- K3: Wo proj + residual + LN1 + LSTMCell(zero state) ----------------
__global__ __launch_bounds__(128) void k_post1(
    const float* __restrict__ h, const float* __restrict__ hattn,
    const float* __restrict__ Wo, const float* __restrict__ bo,
    const float* __restrict__ Wih, const float* __restrict__ bih, const float* __restrict__ bhh,
    const float* __restrict__ ln1g, const float* __restrict__ ln1b,
    float* __restrict__ x2, float* __restrict__ outh, float* __restrict__ outc) {
  __shared__ float arow[4][DD];
  __shared__ float x1s[4][DD];
  __shared__ float redS[4][2], redQ[4][2];
  const int t = threadIdx.x;
  const int i0 = blockIdx.x * 4;
#pragma unroll
  for (int r = 0; r < 4; ++r) arow[r][t] = hattn[(i0 + r) * DD + t];
  __syncthreads();
  float o0 = 0.f, o1 = 0.f, o2 = 0.f, o3 = 0.f;
#pragma unroll 4
  for (int c = 0; c < DD; ++c) {
    float w = Wo[c * DD + t];
    o0 += arow[0][c] * w; o1 += arow[1][c] * w;
    o2 += arow[2][c] * w; o3 += arow[3][c] * w;
  }
  float ovals[4] = {o0, o1, o2, o3};
  const float bov = bo[t], g1 = ln1g[t], b1 = ln1b[t];
#pragma unroll
  for (int r = 0; r < 4; ++r) {
    float res = h[(i0 + r) * DD + t] + ovals[r] + bov;
    float s1 = wred_sum(res), s2 = wred_sum(res * res);
    if ((t & 63) == 0) { redS[r][t >> 6] = s1; redQ[r][t >> 6] = s2; }
    __syncthreads();
    float mu = (redS[r][0] + redS[r][1]) * (1.f / 128.f);
    float var = (redQ[r][0] + redQ[r][1]) * (1.f / 128.f) - mu * mu;
    x1s[r][t] = g1 * (res - mu) * rsqrtf(var + 1e-5f) + b1;
  }
  __syncthreads();
  float gi[4] = {0, 0, 0, 0}, gg[4] = {0, 0, 0, 0}, go[4] = {0, 0, 0, 0};
  for (int c = 0; c < DD; ++c) {
    float wI = Wih[(t)*DD + c];
    float wG = Wih[(t + 256) * DD + c];
    float wO = Wih[(t + 384) * DD + c];
#pragma unroll
    for (int r = 0; r < 4; ++r) {
      float xv = x1s[r][c];
      gi[r] += xv * wI; gg[r] += xv * wG; go[r] += xv * wO;
    }
  }
  const float biI = bih[t] + bhh[t];
  const float biG = bih[t + 256] + bhh[t + 256];
  const float biO = bih[t + 384] + bhh[t + 384];
#pragma unroll
  for (int r = 0; r < 4; ++r) {
    float iv = 1.f / (1.f + expf(-(gi[r] + biI)));
    float gv = tanhf(gg[r] + biG);
    float ov = 1.f / (1.f + expf(-(go[r] + biO)));
    float cn = iv * gv;
    float hn = ov * tanhf(cn);
    outh[(i0 + r) * DD + t] = hn;
    outc[(i0 + r) * DD + t] = cn;
    x2[(i0 + r) * DD + t] = x1s[r][t] + hn;
  }
}

// ---------------- K4a: GraphNorm partial column sums ----------------
__global__ __launch_bounds__(256) void k_gncol(const float* __restrict__ x2,
                                               float* __restrict__ pS, float* __restrict__ pQ) {
  const int t = threadIdx.x, b = blockIdx.x;
  const int c = t & 127, half = t >> 7;
  const int r0 = b * 16 + half * 8;
  float s = 0.f, qq = 0.f;
#pragma unroll
  for (int r = 0; r < 8; ++r) {
    float v = x2[(r0 + r) * DD + c];
    s += v; qq += v * v;
  }
  pS[(b * 2 + half) * DD + c] = s;
  pQ[(b * 2 + half) * DD + c] = qq;
}

// ---------------- K4b: finalize stats ----------------
__global__ __launch_bounds__(128) void k_gnfin(const float* __restrict__ pS,
                                               const float* __restrict__ pQ,
                                               float* __restrict__ stats) {
  const int c = threadIdx.x;
  float s = 0.f, qq = 0.f;
#pragma unroll 8
  for (int kk = 0; kk < 128; ++kk) { s += pS[kk * DD + c]; qq += pQ[kk * DD + c]; }
  float mu = s * (1.f / 1024.f);
  float var = qq * (1.f / 1024.f) - mu * mu;
  stats[c] = mu;
  stats[DD + c] = rsqrtf(var + 1e-5f);
}

// ---------------- K5: GraphNorm apply + FFN + residual + LN2 ----------------
__global__ __launch_bounds__(256) void k_ffn(
    const float* __restrict__ x2, const float* __restrict__ stats,
    const float* __restrict__ gng, const float* __restrict__ gnb,
    const float* __restrict__ Wf1, const float* __restrict__ bf1,
    const float* __restrict__ Wf2, const float* __restrict__ bf2,
    const float* __restrict__ ln2g, const float* __restrict__ ln2b,
    float* __restrict__ out) {
  __shared__ float x3s[4][DD];
  __shared__ float hid[4][512];
  __shared__ float redC[4][256];
  __shared__ float redS[4][4], redQ[4][4];
  const int t = threadIdx.x;
  const int i0 = blockIdx.x * 4;
  for (int idx = t; idx < 4 * DD; idx += 256) {
    int r = idx >> 7, c = idx & 127;
    float vv = x2[(i0 + r) * DD + c];
    x3s[r][c] = gng[c] * (vv - stats[c]) * stats[DD + c] + gnb[c];
  }
  __syncthreads();
  {
    float a0[4] = {0, 0, 0, 0}, a1[4] = {0, 0, 0, 0};
#pragma unroll 2
    for (int c = 0; c < DD; ++c) {
      float w1 = Wf1[c * 512 + t];
      float w2 = Wf1[c * 512 + t + 256];
#pragma unroll
      for (int r = 0; r < 4; ++r) {
        float xv = x3s[r][c];
        a0[r] += xv * w1; a1[r] += xv * w2;
      }
    }
    float bb1 = bf1[t], bb2 = bf1[t + 256];
#pragma unroll
    for (int r = 0; r < 4; ++r) {
      hid[r][t] = fmaxf(a0[r] + bb1, 0.f);
      hid[r][t + 256] = fmaxf(a1[r] + bb2, 0.f);
    }
  }
  __syncthreads();
  const int d = t & 127, half = t >> 7;
  {
    float a[4] = {0, 0, 0, 0};
    for (int uu = 0; uu < 256; ++uu) {
      int u = half * 256 + uu;
      float w = Wf2[u * DD + d];
#pragma unroll
      for (int r = 0; r < 4; ++r) a[r] += hid[r][u] * w;
    }
#pragma unroll
    for (int r = 0; r < 4; ++r) redC[r][t] = a[r];
  }
  __syncthreads();
  const int lane = t & 63, wvv = t >> 6;
#pragma unroll 1
  for (int r = 0; r < 4; ++r) {
    float z = 0.f;
    if (t < DD) z = x3s[r][t] + redC[r][t] + redC[r][t + 128] + bf2[t];
    float s1 = wred_sum(z), s2 = wred_sum(z * z);
    if (lane == 0) { redS[r][wvv] = s1; redQ[r][wvv] = s2; }
    __syncthreads();
    float sum = redS[r][0] + redS[r][1] + redS[r][2] + redS[r][3];
    float sq = redQ[r][0] + redQ[r][1] + redQ[r][2] + redQ[r][3];
    float mu = sum * (1.f / 128.f);
    float var = sq * (1.f / 128.f) - mu * mu;
    float rs = rsqrtf(var + 1e-5f);
    if (t < DD) out[(i0 + r) * DD + t] = ln2g[t] * (z - mu) * rs + ln2b[t];
  }
}

extern "C" void kernel_launch(void* const* d_in, const int* in_sizes, int n_in,
                              void* d_out, int out_size, void* d_ws, size_t ws_size,
                              hipStream_t stream) {
  const float* h   = (const float*)d_in[0];
  const float* e   = (const float*)d_in[1];
  const float* Wq  = (const float*)d_in[3];
  const float* bq  = (const float*)d_in[4];
  const float* Wk  = (const float*)d_in[5];
  const float* bk  = (const float*)d_in[6];
  const float* Wv  = (const float*)d_in[7];
  const float* bv  = (const float*)d_in[8];
  const float* We  = (const float*)d_in[9];
  const float* be  = (const float*)d_in[10];
  const float* Wo  = (const float*)d_in[11];
  const float* bo  = (const float*)d_in[12];
  const float* Wf1 = (const float*)d_in[13];
  const float* bf1 = (const float*)d_in[14];
  const float* Wf2 = (const float*)d_in[15];
  const float* bf2 = (const float*)d_in[16];
  const float* Wih = (const float*)d_in[17];
  const float* bih = (const float*)d_in[19];
  const float* bhh = (const float*)d_in[20];
  const float* gng = (const float*)d_in[21];
  const float* gnb = (const float*)d_in[22];
  const float* l1g = (const float*)d_in[23];
  const float* l1b = (const float*)d_in[24];
  const float* l2g = (const float*)d_in[25];
  const float* l2b = (const float*)d_in[26];

  float* W = (float*)d_ws;
  float* q     = W;
  float* k     = W + 131072;
  float* v     = W + 262144;
  float* hattn = W + 393216;
  float* x2    = W + 524288;
  float* stats = W + 655360;
  float* pS    = W + 655616;
  float* pQ    = W + 672000;

  float* out  = (float*)d_out;
  float* outh = out + 131072;
  float* outc = out + 262144;

  hipLaunchKernelGGL(k_qkv, dim3(256), dim3(128), 0, stream,
                     h, Wq, bq, Wk, bk, Wv, bv, q, k, v);
  hipLaunchKernelGGL(k_attn, dim3(1024), dim3(256), 0, stream,
                     e, We, be, q, k, v, hattn);
  hipLaunchKernelGGL(k_post1, dim3(256), dim3(128), 0, stream,
                     h, hattn, Wo, bo, Wih, bih, bhh, l1g, l1b, x2, outh, outc);
  hipLaunchKernelGGL(k_gncol, dim3(64), dim3(256), 0, stream, x2, pS, pQ);
  hipLaunchKernelGGL(k_gnfin, dim3(1), dim3(128), 0, stream, pS, pQ, stats);
  hipLaunchKernelGGL(k_ffn, dim3(256), dim3(256), 0, stream,
                     x2, stats, gng, gnb, Wf1, bf1, Wf2, bf2, l2g, l2b, out);
}

// Round 8
// 226.464 us; speedup vs baseline: 1.2972x; 1.2113x over previous
//
#include <hip/hip_runtime.h>
#include <math.h>
#include <float.h>
#include <stdint.h>

#define NN 1024
#define DD 128
#define HH 8
#define HDIM 16
#define KTOP 16
#define SCP 1032            // padded j-stride for h-major sc

typedef float vf4 __attribute__((ext_vector_type(4)));

__device__ __forceinline__ float wred_sum(float v) {
#pragma unroll
  for (int off = 32; off > 0; off >>= 1) v += __shfl_xor(v, off, 64);
  return v;
}

// non-temporal float4 load: streams from HBM without cache fill (e has zero reuse)
__device__ __forceinline__ float4 ntload4(const float* p) {
  vf4 r = __builtin_nontemporal_load((const vf4*)p);
  return make_float4(r.x, r.y, r.z, r.w);
}

// DPP lane-reduce add (VALU pipe, no LDS): v += v[partner]
template <int CTRL>
__device__ __forceinline__ float dpp_add(float v) {
  int x = __builtin_amdgcn_update_dpp(0, __float_as_int(v), CTRL, 0xF, 0xF, true);
  return v + __int_as_float(x);
}
#define DPP_XOR1 0xB1   // quad_perm(1,0,3,2)
#define DPP_XOR2 0x4E   // quad_perm(2,3,0,1)
#define DPP_ROR4 0x124  // row_ror:4 (16-lane row)
#define DPP_ROR8 0x128  // row_ror:8

// ---------------- K1: q,k,v = h @ W{q,k,v} + b ----------------
__global__ __launch_bounds__(128) void k_qkv(
    const float* __restrict__ h,
    const float* __restrict__ Wq, const float* __restrict__ bq,
    const float* __restrict__ Wk, const float* __restrict__ bk,
    const float* __restrict__ Wv, const float* __restrict__ bv,
    float* __restrict__ q, float* __restrict__ k, float* __restrict__ v) {
  __shared__ float hrow[4][DD];
  const int t = threadIdx.x;
  const int i0 = blockIdx.x * 4;
#pragma unroll
  for (int r = 0; r < 4; ++r) hrow[r][t] = h[(i0 + r) * DD + t];
  __syncthreads();
  const float* W[3] = {Wq, Wk, Wv};
  const float* B[3] = {bq, bk, bv};
  float* O[3] = {q, k, v};
#pragma unroll
  for (int m = 0; m < 3; ++m) {
    float a0 = 0.f, a1 = 0.f, a2 = 0.f, a3 = 0.f;
    const float* Wm = W[m];
#pragma unroll 8
    for (int c = 0; c < DD; ++c) {
      float w = Wm[c * DD + t];
      a0 += hrow[0][c] * w; a1 += hrow[1][c] * w;
      a2 += hrow[2][c] * w; a3 += hrow[3][c] * w;
    }
    float b = B[m][t];
    float* Om = O[m];
    Om[(i0 + 0) * DD + t] = a0 + b;
    Om[(i0 + 1) * DD + t] = a1 + b;
    Om[(i0 + 2) * DD + t] = a2 + b;
    Om[(i0 + 3) * DD + t] = a3 + b;
  }
}

// ---------------- K2: fused scores + top-k + softmax + PV ----------------
// Block (128 thr) per node i (R4 winner structure). e streamed HBM->VGPR with
// NON-TEMPORAL loads (no L3 fill; e has zero reuse). k/q/We stay cached.
__global__ __launch_bounds__(128, 2) void k_attn(
    const float* __restrict__ e, const float* __restrict__ We, const float* __restrict__ be,
    const float* __restrict__ q, const float* __restrict__ kk, const float* __restrict__ v,
    float* __restrict__ hattn) {
  __shared__ float sc[HH * SCP];       // 33 KB, h-major padded
  const int tid = threadIdx.x;
  const int lane = tid & 63;
  const int wv = tid >> 6;             // 0..1
  const int i = blockIdx.x;

  const int lrow = lane >> 4;          // 0..3
  const int c16 = lane & 15;           // column chunk
  const int c0 = c16 * 8;              // 8 columns, inside head (c16>>1)'s slice
  const int rb = wv * 8 + lrow;        // rows rb and rb+4 within a 16-row tile

  // weights: We[c0+cl][h] for cl in 0..7 -> 16 f4 regs
  float4 w[16];
#pragma unroll
  for (int cl = 0; cl < 8; ++cl) {
    w[cl * 2]     = *(const float4*)(We + (c0 + cl) * HH);
    w[cl * 2 + 1] = *(const float4*)(We + (c0 + cl) * HH + 4);
  }
  // q slice (pre-scaled by 1/sqrt(16)); head h=c16>>1, dims c0..c0+8
  float4 q0 = *(const float4*)(q + (size_t)i * DD + c0);
  float4 q1 = *(const float4*)(q + (size_t)i * DD + c0 + 4);
  q0.x *= 0.25f; q0.y *= 0.25f; q0.z *= 0.25f; q0.w *= 0.25f;
  q1.x *= 0.25f; q1.y *= 0.25f; q1.z *= 0.25f; q1.w *= 0.25f;
  const float behv = be[c16 >> 1];

  const float* ei = e + ((size_t)i << 17);
  const float* pa = ei + (size_t)rb * DD + c0;   // row a, tile 0
  const float* pb = pa + 4 * DD;                 // row b (rb+4)
  const float* ka = kk + (size_t)rb * DD + c0;
  const float* kb = ka + 4 * DD;

  // prologue: iter 0 loads (e non-temporal, k cached)
  float4 ea0 = ntload4(pa);          float4 ea1 = ntload4(pa + 4);
  float4 eb0 = ntload4(pb);          float4 eb1 = ntload4(pb + 4);
  float4 Ka0 = *(const float4*)(ka); float4 Ka1 = *(const float4*)(ka + 4);
  float4 Kb0 = *(const float4*)(kb); float4 Kb1 = *(const float4*)(kb + 4);

  for (int t = 0; t < 64; ++t) {       // 64 tiles x 16 rows
    float4 na0, na1, nb0, nb1, nKa0, nKa1, nKb0, nKb1;
    const bool more = (t + 1 < 64);
    if (more) {                        // depth-1 prefetch of tile t+1
      const float* xa = pa + (size_t)(t + 1) * (16 * DD);
      const float* xb = xa + 4 * DD;
      const float* ya = ka + (size_t)(t + 1) * (16 * DD);
      const float* yb = ya + 4 * DD;
      na0 = ntload4(xa);  na1 = ntload4(xa + 4);
      nb0 = ntload4(xb);  nb1 = ntload4(xb + 4);
      nKa0 = *(const float4*)(ya); nKa1 = *(const float4*)(ya + 4);
      nKb0 = *(const float4*)(yb); nKb1 = *(const float4*)(yb + 4);
    }

    float acca[8] = {0,0,0,0,0,0,0,0};
    float accb[8] = {0,0,0,0,0,0,0,0};
    const float eva[8] = {ea0.x, ea0.y, ea0.z, ea0.w, ea1.x, ea1.y, ea1.z, ea1.w};
    const float evb[8] = {eb0.x, eb0.y, eb0.z, eb0.w, eb1.x, eb1.y, eb1.z, eb1.w};
#pragma unroll
    for (int cl = 0; cl < 8; ++cl) {
      float4 wlo = w[cl * 2], whi = w[cl * 2 + 1];
      float a = eva[cl], b = evb[cl];
      acca[0] += a * wlo.x; acca[1] += a * wlo.y; acca[2] += a * wlo.z; acca[3] += a * wlo.w;
      acca[4] += a * whi.x; acca[5] += a * whi.y; acca[6] += a * whi.z; acca[7] += a * whi.w;
      accb[0] += b * wlo.x; accb[1] += b * wlo.y; accb[2] += b * wlo.z; accb[3] += b * wlo.w;
      accb[4] += b * whi.x; accb[5] += b * whi.y; accb[6] += b * whi.z; accb[7] += b * whi.w;
    }
    float qka = q0.x*Ka0.x + q0.y*Ka0.y + q0.z*Ka0.z + q0.w*Ka0.w
              + q1.x*Ka1.x + q1.y*Ka1.y + q1.z*Ka1.z + q1.w*Ka1.w;
    float qkb = q0.x*Kb0.x + q0.y*Kb0.y + q0.z*Kb0.z + q0.w*Kb0.w
              + q1.x*Kb1.x + q1.y*Kb1.y + q1.z*Kb1.z + q1.w*Kb1.w;

    // allreduce over the 16 lanes of this DPP row (VALU pipe)
#pragma unroll
    for (int hh = 0; hh < 8; ++hh) {
      acca[hh] = dpp_add<DPP_XOR1>(acca[hh]);
      acca[hh] = dpp_add<DPP_XOR2>(acca[hh]);
      acca[hh] = dpp_add<DPP_ROR4>(acca[hh]);
      acca[hh] = dpp_add<DPP_ROR8>(acca[hh]);
      accb[hh] = dpp_add<DPP_XOR1>(accb[hh]);
      accb[hh] = dpp_add<DPP_XOR2>(accb[hh]);
      accb[hh] = dpp_add<DPP_ROR4>(accb[hh]);
      accb[hh] = dpp_add<DPP_ROR8>(accb[hh]);
    }
    qka = dpp_add<DPP_XOR1>(qka);   // head = c16>>1 spans lanes {2h,2h+1}
    qkb = dpp_add<DPP_XOR1>(qkb);

    if ((c16 & 1) == 0) {            // writer lane c16=2h holds acc[h] and qk(h)
      const int h = c16 >> 1;
      float sa = acca[0], sb = accb[0];
#pragma unroll
      for (int hh = 1; hh < 8; ++hh) {
        if (h == hh) { sa = acca[hh]; sb = accb[hh]; }
      }
      const int j = t * 16 + rb;
      sc[h * SCP + j]     = sa + qka + behv;
      sc[h * SCP + j + 4] = sb + qkb + behv;
    }

    if (more) {
      ea0 = na0; ea1 = na1; eb0 = nb0; eb1 = nb1;
      Ka0 = nKa0; Ka1 = nKa1; Kb0 = nKb0; Kb1 = nKb1;
    }
  }
  __syncthreads();

  // ---- phase 3: per head top-16 (lowest-j ties), softmax, PV ----
#pragma unroll 1
  for (int hp = 0; hp < 4; ++hp) {
    const int h = wv * 4 + hp;
    float val[16];
#pragma unroll
    for (int s = 0; s < 16; ++s) val[s] = sc[h * SCP + s * 64 + lane];
    int selj[16];
    float wgt[16];
    float vmax = 0.f, denom = 0.f;
#pragma unroll
    for (int t = 0; t < KTOP; ++t) {
      float bv = -FLT_MAX;
      int bj = 0x7FFFFFFF;
#pragma unroll
      for (int s = 0; s < 16; ++s) {
        float vs = val[s];
        int jj = s * 64 + lane;
        if (vs > bv) { bv = vs; bj = jj; }
      }
#pragma unroll
      for (int off = 32; off > 0; off >>= 1) {
        float ov = __shfl_xor(bv, off, 64);
        int oj = __shfl_xor(bj, off, 64);
        if (ov > bv || (ov == bv && oj < bj)) { bv = ov; bj = oj; }
      }
      selj[t] = bj;
      if (t == 0) vmax = bv;
      float wexp = expf(bv - vmax);
      wgt[t] = wexp;
      denom += wexp;
      const int so = bj >> 6;
      if ((bj & 63) == lane) {
#pragma unroll
        for (int s = 0; s < 16; ++s)
          if (s == so) val[s] = -FLT_MAX;
      }
    }
    const float inv = 1.0f / denom;
    const int d = lane & 15;
    float acc = 0.f;
#pragma unroll
    for (int t = 0; t < KTOP; ++t)
      acc += wgt[t] * v[(size_t)selj[t] * DD + h * HDIM + d];
    if (lane < 16) hattn[i * DD + h * HDIM + d] = acc * inv;
  }
}

// ---------------- K3: Wo proj + residual + LN1 + LSTMCell(zero state) ----------------
__global__ __launch_bounds__(128) void k_post1(
    const float* __restrict__ h, const float* __restrict__ hattn,
    const float* __restrict__ Wo, const float* __restrict__ bo,
    const float* __restrict__ Wih, const float* __restrict__ bih, const float* __restrict__ bhh,
    const float* __restrict__ ln1g, const float* __restrict__ ln1b,
    float* __restrict__ x2, float* __restrict__ outh, float* __restrict__ outc) {
  __shared__ float arow[4][DD];
  __shared__ float x1s[4][DD];
  __shared__ float redS[4][2], redQ[4][2];
  const int t = threadIdx.x;
  const int i0 = blockIdx.x * 4;
#pragma unroll
  for (int r = 0; r < 4; ++r) arow[r][t] = hattn[(i0 + r) * DD + t];
  __syncthreads();
  float o0 = 0.f, o1 = 0.f, o2 = 0.f, o3 = 0.f;
#pragma unroll 4
  for (int c = 0; c < DD; ++c) {
    float w = Wo[c * DD + t];
    o0 += arow[0][c] * w; o1 += arow[1][c] * w;
    o2 += arow[2][c] * w; o3 += arow[3][c] * w;
  }
  float ovals[4] = {o0, o1, o2, o3};
  const float bov = bo[t], g1 = ln1g[t], b1 = ln1b[t];
#pragma unroll
  for (int r = 0; r < 4; ++r) {
    float res = h[(i0 + r) * DD + t] + ovals[r] + bov;
    float s1 = wred_sum(res), s2 = wred_sum(res * res);
    if ((t & 63) == 0) { redS[r][t >> 6] = s1; redQ[r][t >> 6] = s2; }
    __syncthreads();
    float mu = (redS[r][0] + redS[r][1]) * (1.f / 128.f);
    float var = (redQ[r][0] + redQ[r][1]) * (1.f / 128.f) - mu * mu;
    x1s[r][t] = g1 * (res - mu) * rsqrtf(var + 1e-5f) + b1;
  }
  __syncthreads();
  float gi[4] = {0, 0, 0, 0}, gg[4] = {0, 0, 0, 0}, go[4] = {0, 0, 0, 0};
  for (int c = 0; c < DD; ++c) {
    float wI = Wih[(t)*DD + c];
    float wG = Wih[(t + 256) * DD + c];
    float wO = Wih[(t + 384) * DD + c];
#pragma unroll
    for (int r = 0; r < 4; ++r) {
      float xv = x1s[r][c];
      gi[r] += xv * wI; gg[r] += xv * wG; go[r] += xv * wO;
    }
  }
  const float biI = bih[t] + bhh[t];
  const float biG = bih[t + 256] + bhh[t + 256];
  const float biO = bih[t + 384] + bhh[t + 384];
#pragma unroll
  for (int r = 0; r < 4; ++r) {
    float iv = 1.f / (1.f + expf(-(gi[r] + biI)));
    float gv = tanhf(gg[r] + biG);
    float ov = 1.f / (1.f + expf(-(go[r] + biO)));
    float cn = iv * gv;
    float hn = ov * tanhf(cn);
    outh[(i0 + r) * DD + t] = hn;
    outc[(i0 + r) * DD + t] = cn;
    x2[(i0 + r) * DD + t] = x1s[r][t] + hn;
  }
}

// ---------------- K4a: GraphNorm partial column sums ----------------
__global__ __launch_bounds__(256) void k_gncol(const float* __restrict__ x2,
                                               float* __restrict__ pS, float* __restrict__ pQ) {
  const int t = threadIdx.x, b = blockIdx.x;
  const int c = t & 127, half = t >> 7;
  const int r0 = b * 16 + half * 8;
  float s = 0.f, qq = 0.f;
#pragma unroll
  for (int r = 0; r < 8; ++r) {
    float v = x2[(r0 + r) * DD + c];
    s += v; qq += v * v;
  }
  pS[(b * 2 + half) * DD + c] = s;
  pQ[(b * 2 + half) * DD + c] = qq;
}

// ---------------- K4b: finalize stats ----------------
__global__ __launch_bounds__(128) void k_gnfin(const float* __restrict__ pS,
                                               const float* __restrict__ pQ,
                                               float* __restrict__ stats) {
  const int c = threadIdx.x;
  float s = 0.f, qq = 0.f;
#pragma unroll 8
  for (int kk = 0; kk < 128; ++kk) { s += pS[kk * DD + c]; qq += pQ[kk * DD + c]; }
  float mu = s * (1.f / 1024.f);
  float var = qq * (1.f / 1024.f) - mu * mu;
  stats[c] = mu;
  stats[DD + c] = rsqrtf(var + 1e-5f);
}

// ---------------- K5: GraphNorm apply + FFN + residual + LN2 ----------------
__global__ __launch_bounds__(256) void k_ffn(
    const float* __restrict__ x2, const float* __restrict__ stats,
    const float* __restrict__ gng, const float* __restrict__ gnb,
    const float* __restrict__ Wf1, const float* __restrict__ bf1,
    const float* __restrict__ Wf2, const float* __restrict__ bf2,
    const float* __restrict__ ln2g, const float* __restrict__ ln2b,
    float* __restrict__ out) {
  __shared__ float x3s[4][DD];
  __shared__ float hid[4][512];
  __shared__ float redC[4][256];
  __shared__ float redS[4][4], redQ[4][4];
  const int t = threadIdx.x;
  const int i0 = blockIdx.x * 4;
  for (int idx = t; idx < 4 * DD; idx += 256) {
    int r = idx >> 7, c = idx & 127;
    float vv = x2[(i0 + r) * DD + c];
    x3s[r][c] = gng[c] * (vv - stats[c]) * stats[DD + c] + gnb[c];
  }
  __syncthreads();
  {
    float a0[4] = {0, 0, 0, 0}, a1[4] = {0, 0, 0, 0};
#pragma unroll 2
    for (int c = 0; c < DD; ++c) {
      float w1 = Wf1[c * 512 + t];
      float w2 = Wf1[c * 512 + t + 256];
#pragma unroll
      for (int r = 0; r < 4; ++r) {
        float xv = x3s[r][c];
        a0[r] += xv * w1; a1[r] += xv * w2;
      }
    }
    float bb1 = bf1[t], bb2 = bf1[t + 256];
#pragma unroll
    for (int r = 0; r < 4; ++r) {
      hid[r][t] = fmaxf(a0[r] + bb1, 0.f);
      hid[r][t + 256] = fmaxf(a1[r] + bb2, 0.f);
    }
  }
  __syncthreads();
  const int d = t & 127, half = t >> 7;
  {
    float a[4] = {0, 0, 0, 0};
    for (int uu = 0; uu < 256; ++uu) {
      int u = half * 256 + uu;
      float w = Wf2[u * DD + d];
#pragma unroll
      for (int r = 0; r < 4; ++r) a[r] += hid[r][u] * w;
    }
#pragma unroll
    for (int r = 0; r < 4; ++r) redC[r][t] = a[r];
  }
  __syncthreads();
  const int lane = t & 63, wvv = t >> 6;
#pragma unroll 1
  for (int r = 0; r < 4; ++r) {
    float z = 0.f;
    if (t < DD) z = x3s[r][t] + redC[r][t] + redC[r][t + 128] + bf2[t];
    float s1 = wred_sum(z), s2 = wred_sum(z * z);
    if (lane == 0) { redS[r][wvv] = s1; redQ[r][wvv] = s2; }
    __syncthreads();
    float sum = redS[r][0] + redS[r][1] + redS[r][2] + redS[r][3];
    float sq = redQ[r][0] + redQ[r][1] + redQ[r][2] + redQ[r][3];
    float mu = sum * (1.f / 128.f);
    float var = sq * (1.f / 128.f) - mu * mu;
    float rs = rsqrtf(var + 1e-5f);
    if (t < DD) out[(i0 + r) * DD + t] = ln2g[t] * (z - mu) * rs + ln2b[t];
  }
}

extern "C" void kernel_launch(void* const* d_in, const int* in_sizes, int n_in,
                              void* d_out, int out_size, void* d_ws, size_t ws_size,
                              hipStream_t stream) {
  const float* h   = (const float*)d_in[0];
  const float* e   = (const float*)d_in[1];
  const float* Wq  = (const float*)d_in[3];
  const float* bq  = (const float*)d_in[4];
  const float* Wk  = (const float*)d_in[5];
  const float* bk  = (const float*)d_in[6];
  const float* Wv  = (const float*)d_in[7];
  const float* bv  = (const float*)d_in[8];
  const float* We  = (const float*)d_in[9];
  const float* be  = (const float*)d_in[10];
  const float* Wo  = (const float*)d_in[11];
  const float* bo  = (const float*)d_in[12];
  const float* Wf1 = (const float*)d_in[13];
  const float* bf1 = (const float*)d_in[14];
  const float* Wf2 = (const float*)d_in[15];
  const float* bf2 = (const float*)d_in[16];
  const float* Wih = (const float*)d_in[17];
  const float* bih = (const float*)d_in[19];
  const float* bhh = (const float*)d_in[20];
  const float* gng = (const float*)d_in[21];
  const float* gnb = (const float*)d_in[22];
  const float* l1g = (const float*)d_in[23];
  const float* l1b = (const float*)d_in[24];
  const float* l2g = (const float*)d_in[25];
  const float* l2b = (const float*)d_in[26];

  float* W = (float*)d_ws;
  float* q     = W;
  float* k     = W + 131072;
  float* v     = W + 262144;
  float* hattn = W + 393216;
  float* x2    = W + 524288;
  float* stats = W + 655360;
  float* pS    = W + 655616;
  float* pQ    = W + 672000;

  float* out  = (float*)d_out;
  float* outh = out + 131072;
  float* outc = out + 262144;

  hipLaunchKernelGGL(k_qkv, dim3(256), dim3(128), 0, stream,
                     h, Wq, bq, Wk, bk, Wv, bv, q, k, v);
  hipLaunchKernelGGL(k_attn, dim3(1024), dim3(128), 0, stream,
                     e, We, be, q, k, v, hattn);
  hipLaunchKernelGGL(k_post1, dim3(256), dim3(128), 0, stream,
                     h, hattn, Wo, bo, Wih, bih, bhh, l1g, l1b, x2, outh, outc);
  hipLaunchKernelGGL(k_gncol, dim3(64), dim3(256), 0, stream, x2, pS, pQ);
  hipLaunchKernelGGL(k_gnfin, dim3(1), dim3(128), 0, stream, pS, pQ, stats);
  hipLaunchKernelGGL(k_ffn, dim3(256), dim3(256), 0, stream,
                     x2, stats, gng, gnb, Wf1, bf1, Wf2, bf2, l2g, l2b, out);
}